// Round 1
// baseline (783.661 us; speedup 1.0000x reference)
//
#include <hip/hip_runtime.h>

typedef __bf16 bf16x8 __attribute__((ext_vector_type(8)));
typedef __bf16 bf16x4 __attribute__((ext_vector_type(4)));
typedef float  f32x4  __attribute__((ext_vector_type(4)));

#define LOG2E 1.4426950408889634f

__device__ __forceinline__ void gload16(const void* g, void* l) {
  __builtin_amdgcn_global_load_lds((const __attribute__((address_space(1))) void*)g,
                                   (__attribute__((address_space(3))) void*)l, 16, 0, 0);
}

// ---------------- f32 -> bf16 elementwise convert (x) ----------------
__global__ __launch_bounds__(256) void cvt4(const float* __restrict__ in,
                                            __bf16* __restrict__ outp, int n4) {
  int i = blockIdx.x * blockDim.x + threadIdx.x;
  if (i < n4) {
    float4 v = ((const float4*)in)[i];
    bf16x4 o = { (__bf16)v.x, (__bf16)v.y, (__bf16)v.z, (__bf16)v.w };
    *(bf16x4*)(outp + (size_t)i * 4) = o;
  }
}

// ---------------- f32 [K,N] -> bf16 [N,K] transpose-convert ----------------
__global__ __launch_bounds__(256) void transcvt(const float* __restrict__ w,
                                                __bf16* __restrict__ wt,
                                                int K, int N) {
  __shared__ float tile[32][33];
  const int n0 = blockIdx.x * 32, k0 = blockIdx.y * 32;
  const int tx = threadIdx.x, ty = threadIdx.y;
#pragma unroll
  for (int i = 0; i < 4; ++i)
    tile[ty + i * 8][tx] = w[(size_t)(k0 + ty + i * 8) * N + n0 + tx];
  __syncthreads();
#pragma unroll
  for (int i = 0; i < 4; ++i)
    wt[(size_t)(n0 + ty + i * 8) * K + k0 + tx] = (__bf16)tile[tx][ty + i * 8];
}

// ---------------- bf16 GEMM: C = A[M,K] * Bt[N,K]^T (+bias) ----------------
// EPI=0: qkv epilogue -> scatter Q(scaled),K as [B,H,T,D] bf16 and V^T [B,H,D,T] bf16
// EPI=1: f32 out += bias, row-major [M, NCOLS]
template <int EPI, int NCOLS>
__global__ __launch_bounds__(256, 2)
void gemm_bt(const __bf16* __restrict__ A, const __bf16* __restrict__ Bt,
             const float* __restrict__ bias,
             __bf16* __restrict__ Qb, __bf16* __restrict__ Kb,
             __bf16* __restrict__ Vtb, float* __restrict__ Out) {
  constexpr int K = 2048;
  __shared__ __align__(16) __bf16 As[128 * 64];
  __shared__ __align__(16) __bf16 Bs[128 * 64];
  const int tid = threadIdx.x, lane = tid & 63, w = tid >> 6;
  const int wr = w >> 1, wc = w & 1;
  const int by = blockIdx.y, bx = blockIdx.x;
  const __bf16* Ab = A + (size_t)by * 128 * K;
  const __bf16* Bb = Bt + (size_t)bx * 128 * K;
  f32x4 acc[4][4] = {};

  for (int k0 = 0; k0 < K; k0 += 64) {
#pragma unroll
    for (int c = 0; c < 4; ++c) {
      int idx = c * 256 + tid;
      int row = idx >> 3, col = (idx & 7) * 8;
      gload16(Ab + (size_t)row * K + k0 + col, (void*)(As + idx * 8));
      gload16(Bb + (size_t)row * K + k0 + col, (void*)(Bs + idx * 8));
    }
    __syncthreads();
#pragma unroll
    for (int kk = 0; kk < 64; kk += 32) {
      const int ko = kk + (lane >> 4) * 8;
      bf16x8 a[4], b[4];
#pragma unroll
      for (int i = 0; i < 4; ++i)
        a[i] = *(const bf16x8*)(As + (wr * 64 + i * 16 + (lane & 15)) * 64 + ko);
#pragma unroll
      for (int i = 0; i < 4; ++i)
        b[i] = *(const bf16x8*)(Bs + (wc * 64 + i * 16 + (lane & 15)) * 64 + ko);
#pragma unroll
      for (int mi = 0; mi < 4; ++mi)
#pragma unroll
        for (int ni = 0; ni < 4; ++ni)
          acc[mi][ni] = __builtin_amdgcn_mfma_f32_16x16x32_bf16(a[mi], b[ni],
                                                                acc[mi][ni], 0, 0, 0);
    }
    __syncthreads();
  }

  // epilogue: C frag layout col = lane&15, row = (lane>>4)*4 + j (m89-verified)
  const int r0 = by * 128 + wr * 64 + ((lane >> 4) << 2);
  const int c0 = bx * 128 + wc * 64 + (lane & 15);
#pragma unroll
  for (int ni = 0; ni < 4; ++ni) {
    const int c = c0 + ni * 16;
    const float bv = bias[c];
    if constexpr (EPI == 0) {
      const int sel = c >> 11, cc = c & 2047, h = cc >> 7, d = cc & 127;
#pragma unroll
      for (int mi = 0; mi < 4; ++mi) {
        const int r = r0 + mi * 16;
        const int bb = r >> 11, t = r & 2047;
        if (sel == 2) {
          bf16x4 pv;
#pragma unroll
          for (int j = 0; j < 4; ++j) pv[j] = (__bf16)(acc[mi][ni][j] + bv);
          *(bf16x4*)(Vtb + ((size_t)(bb * 16 + h) * 128 + d) * 2048 + t) = pv;
        } else {
          __bf16* dst = (sel == 0 ? Qb : Kb) + ((size_t)(bb * 16 + h) * 2048 + t) * 128 + d;
          const float sc = (sel == 0) ? 0.08838834764831845f : 1.0f;  // 1/sqrt(128)
#pragma unroll
          for (int j = 0; j < 4; ++j)
            dst[(size_t)j * 128] = (__bf16)((acc[mi][ni][j] + bv) * sc);
        }
      }
    } else {
#pragma unroll
      for (int mi = 0; mi < 4; ++mi) {
        const int r = r0 + mi * 16;
#pragma unroll
        for (int j = 0; j < 4; ++j)
          Out[(size_t)(r + j) * NCOLS + c] = acc[mi][ni][j] + bv;
      }
    }
  }
}

// ---------------- causal flash attention ----------------
// grid (T/64, B*H); 4 waves/block, each wave owns 16 q-rows; KVBLK = 64
__global__ __launch_bounds__(256, 2)
void attn_fwd(const __bf16* __restrict__ Qb, const __bf16* __restrict__ Kb,
              const __bf16* __restrict__ Vtb, __bf16* __restrict__ Yb) {
  const int qt = blockIdx.x, bh = blockIdx.y;
  const int bidx = bh >> 4, h = bh & 15;
  const int tid = threadIdx.x, lane = tid & 63, w = tid >> 6;
  __shared__ __align__(16) __bf16 Kl[64 * 136];    // K tile [64][128] pad->136
  __shared__ __align__(16) __bf16 Vl[128 * 72];    // V^T tile [128][64] pad->72
  __shared__ __align__(16) __bf16 Pl[4][16 * 72];  // per-wave P [16][64] pad->72

  const __bf16* Qh = Qb + ((size_t)bh * 2048 + qt * 64) * 128;
  const __bf16* Kh = Kb + (size_t)bh * 2048 * 128;
  const __bf16* Vh = Vtb + (size_t)bh * 128 * 2048;

  // Q fragments in registers: A-frag row = lane&15, k = kk*32 + (lane>>4)*8
  bf16x8 qf[4];
  {
    const int qrow = w * 16 + (lane & 15);
#pragma unroll
    for (int kk = 0; kk < 4; ++kk)
      qf[kk] = *(const bf16x8*)(Qh + (size_t)qrow * 128 + kk * 32 + (lane >> 4) * 8);
  }

  f32x4 accO[8] = {};
  float mrow[4], lrow[4];
#pragma unroll
  for (int j = 0; j < 4; ++j) { mrow[j] = -3.0e38f; lrow[j] = 0.f; }

  for (int kvt = 0; kvt <= qt; ++kvt) {
    const int kv0 = kvt * 64;
    __syncthreads();  // protect LDS tiles from previous iteration's readers
    // stage K [64][128] (reg-staged so LDS can be padded)
#pragma unroll
    for (int c2 = 0; c2 < 4; ++c2) {
      int idx = c2 * 256 + tid;
      int row = idx >> 4, col = (idx & 15) * 8;
      *(uint4*)(Kl + row * 136 + col) =
          *(const uint4*)(Kh + (size_t)(kv0 + row) * 128 + col);
    }
    // stage V^T [128][64]
#pragma unroll
    for (int c2 = 0; c2 < 4; ++c2) {
      int idx = c2 * 256 + tid;
      int row = idx >> 3, col = (idx & 7) * 8;
      *(uint4*)(Vl + row * 72 + col) =
          *(const uint4*)(Vh + (size_t)row * 2048 + kv0 + col);
    }
    __syncthreads();

    // S = Q K^T : acc col = kv (lane&15 + n*16), row = q ((lane>>4)*4 + j)
    f32x4 s[4] = {};
#pragma unroll
    for (int kk = 0; kk < 4; ++kk) {
      const int ko = kk * 32 + (lane >> 4) * 8;
#pragma unroll
      for (int n = 0; n < 4; ++n) {
        bf16x8 bf = *(const bf16x8*)(Kl + (n * 16 + (lane & 15)) * 136 + ko);
        s[n] = __builtin_amdgcn_mfma_f32_16x16x32_bf16(qf[kk], bf, s[n], 0, 0, 0);
      }
    }

    if (kvt == qt) {  // diagonal tile: causal mask
      const int qg = qt * 64 + w * 16 + ((lane >> 4) << 2);
      const int kvg = kv0 + (lane & 15);
#pragma unroll
      for (int n = 0; n < 4; ++n)
#pragma unroll
        for (int j = 0; j < 4; ++j)
          if (kvg + n * 16 > qg + j) s[n][j] = -3.0e38f;
    }

    // wave-parallel row max over 64 cols (16 lanes * 4 frags)
    float pm[4];
#pragma unroll
    for (int j = 0; j < 4; ++j)
      pm[j] = fmaxf(fmaxf(s[0][j], s[1][j]), fmaxf(s[2][j], s[3][j]));
#pragma unroll
    for (int off = 1; off < 16; off <<= 1)
#pragma unroll
      for (int j = 0; j < 4; ++j)
        pm[j] = fmaxf(pm[j], __shfl_xor(pm[j], off, 64));

    float corr[4];
#pragma unroll
    for (int j = 0; j < 4; ++j) {
      float mnew = fmaxf(mrow[j], pm[j]);
      corr[j] = exp2f((mrow[j] - mnew) * LOG2E);
      mrow[j] = mnew;
    }

    float rs[4] = {0.f, 0.f, 0.f, 0.f};
#pragma unroll
    for (int n = 0; n < 4; ++n)
#pragma unroll
      for (int j = 0; j < 4; ++j) {
        float p = exp2f((s[n][j] - mrow[j]) * LOG2E);
        s[n][j] = p;
        rs[j] += p;
      }
#pragma unroll
    for (int off = 1; off < 16; off <<= 1)
#pragma unroll
      for (int j = 0; j < 4; ++j) rs[j] += __shfl_xor(rs[j], off, 64);
#pragma unroll
    for (int j = 0; j < 4; ++j) lrow[j] = lrow[j] * corr[j] + rs[j];

#pragma unroll
    for (int n = 0; n < 8; ++n)
#pragma unroll
      for (int j = 0; j < 4; ++j) accO[n][j] *= corr[j];

    // repack P through per-wave LDS into A-fragment layout
    {
      const int prow = ((lane >> 4) << 2);
#pragma unroll
      for (int n = 0; n < 4; ++n)
#pragma unroll
        for (int j = 0; j < 4; ++j)
          Pl[w][(prow + j) * 72 + n * 16 + (lane & 15)] = (__bf16)s[n][j];
    }

    // O += P @ V : B[k=t][n=d] = V^T[d][t] rows, contiguous in t
#pragma unroll
    for (int kk = 0; kk < 2; ++kk) {
      const int ko = kk * 32 + (lane >> 4) * 8;
      bf16x8 af = *(const bf16x8*)(&Pl[w][(lane & 15) * 72 + ko]);
#pragma unroll
      for (int n = 0; n < 8; ++n) {
        bf16x8 bf = *(const bf16x8*)(Vl + (n * 16 + (lane & 15)) * 72 + ko);
        accO[n] = __builtin_amdgcn_mfma_f32_16x16x32_bf16(af, bf, accO[n], 0, 0, 0);
      }
    }
  }

  // normalize and write y[b, t, h*128 + d] bf16
  float rl[4];
#pragma unroll
  for (int j = 0; j < 4; ++j) rl[j] = 1.0f / lrow[j];
  const int t0 = qt * 64 + w * 16 + ((lane >> 4) << 2);
#pragma unroll
  for (int n = 0; n < 8; ++n)
#pragma unroll
    for (int j = 0; j < 4; ++j)
      Yb[((size_t)bidx * 2048 + t0 + j) * 2048 + h * 128 + n * 16 + (lane & 15)] =
          (__bf16)(accO[n][j] * rl[j]);
}

// ---------------- launch ----------------
extern "C" void kernel_launch(void* const* d_in, const int* in_sizes, int n_in,
                              void* d_out, int out_size, void* d_ws, size_t ws_size,
                              hipStream_t stream) {
  const float* x      = (const float*)d_in[0];
  const float* w_attn = (const float*)d_in[1];
  const float* b_attn = (const float*)d_in[2];
  const float* w_proj = (const float*)d_in[3];
  const float* b_proj = (const float*)d_in[4];
  float* out = (float*)d_out;

  // workspace layout (bf16 elements); total = 159,383,552 bytes
  __bf16* Qb  = (__bf16*)d_ws;                 // [B,H,T,D]
  __bf16* Kb  = Qb  + (size_t)16777216;        // [B,H,T,D]
  __bf16* Vtb = Kb  + (size_t)16777216;        // [B,H,D,T]
  __bf16* XYb = Vtb + (size_t)16777216;        // x_bf16, later y_bf16 [B,T,C]
  __bf16* Wt  = XYb + (size_t)16777216;        // w_attn^T [6144,2048] / w_proj^T [2048,2048]

  cvt4<<<dim3(16384), dim3(256), 0, stream>>>(x, XYb, 4194304);
  transcvt<<<dim3(192, 64), dim3(32, 8), 0, stream>>>(w_attn, Wt, 2048, 6144);
  gemm_bt<0, 6144><<<dim3(48, 64), dim3(256), 0, stream>>>(XYb, Wt, b_attn,
                                                           Qb, Kb, Vtb, nullptr);
  transcvt<<<dim3(64, 64), dim3(32, 8), 0, stream>>>(w_proj, Wt, 2048, 2048);
  attn_fwd<<<dim3(32, 64), dim3(256), 0, stream>>>(Qb, Kb, Vtb, XYb);
  gemm_bt<1, 2048><<<dim3(16, 64), dim3(256), 0, stream>>>(XYb, Wt, b_proj,
                                                           nullptr, nullptr, nullptr, out);
}

// Round 2
// 766.047 us; speedup vs baseline: 1.0230x; 1.0230x over previous
//
#include <hip/hip_runtime.h>

typedef __bf16 bf16x8 __attribute__((ext_vector_type(8)));
typedef __bf16 bf16x4 __attribute__((ext_vector_type(4)));
typedef float  f32x4  __attribute__((ext_vector_type(4)));

#define LOG2E 1.4426950408889634f

__device__ __forceinline__ void gload16(const void* g, void* l) {
  __builtin_amdgcn_global_load_lds((const __attribute__((address_space(1))) void*)g,
                                   (__attribute__((address_space(3))) void*)l, 16, 0, 0);
}

// ---------------- f32 -> bf16 elementwise convert (x) ----------------
__global__ __launch_bounds__(256) void cvt4(const float* __restrict__ in,
                                            __bf16* __restrict__ outp, int n4) {
  int i = blockIdx.x * blockDim.x + threadIdx.x;
  if (i < n4) {
    float4 v = ((const float4*)in)[i];
    bf16x4 o = { (__bf16)v.x, (__bf16)v.y, (__bf16)v.z, (__bf16)v.w };
    *(bf16x4*)(outp + (size_t)i * 4) = o;
  }
}

// ---------------- f32 [K,N] -> bf16 [N,K] transpose-convert ----------------
__global__ __launch_bounds__(256) void transcvt(const float* __restrict__ w,
                                                __bf16* __restrict__ wt,
                                                int K, int N) {
  __shared__ float tile[32][33];
  const int n0 = blockIdx.x * 32, k0 = blockIdx.y * 32;
  const int tx = threadIdx.x, ty = threadIdx.y;
#pragma unroll
  for (int i = 0; i < 4; ++i)
    tile[ty + i * 8][tx] = w[(size_t)(k0 + ty + i * 8) * N + n0 + tx];
  __syncthreads();
#pragma unroll
  for (int i = 0; i < 4; ++i)
    wt[(size_t)(n0 + ty + i * 8) * K + k0 + tx] = (__bf16)tile[tx][ty + i * 8];
}

// ---------------- bf16 GEMM: C = A[M,K] * Bt[N,K]^T (+bias) ----------------
template <int EPI, int NCOLS>
__global__ __launch_bounds__(256, 2)
void gemm_bt(const __bf16* __restrict__ A, const __bf16* __restrict__ Bt,
             const float* __restrict__ bias,
             __bf16* __restrict__ Qb, __bf16* __restrict__ Kb,
             __bf16* __restrict__ Vtb, float* __restrict__ Out) {
  constexpr int K = 2048;
  __shared__ __align__(16) __bf16 As[128 * 64];
  __shared__ __align__(16) __bf16 Bs[128 * 64];
  const int tid = threadIdx.x, lane = tid & 63, w = tid >> 6;
  const int wr = w >> 1, wc = w & 1;
  const int by = blockIdx.y, bx = blockIdx.x;
  const __bf16* Ab = A + (size_t)by * 128 * K;
  const __bf16* Bb = Bt + (size_t)bx * 128 * K;
  f32x4 acc[4][4] = {};

  for (int k0 = 0; k0 < K; k0 += 64) {
#pragma unroll
    for (int c = 0; c < 4; ++c) {
      int idx = c * 256 + tid;
      int row = idx >> 3, col = (idx & 7) * 8;
      gload16(Ab + (size_t)row * K + k0 + col, (void*)(As + idx * 8));
      gload16(Bb + (size_t)row * K + k0 + col, (void*)(Bs + idx * 8));
    }
    __syncthreads();
#pragma unroll
    for (int kk = 0; kk < 64; kk += 32) {
      const int ko = kk + (lane >> 4) * 8;
      bf16x8 a[4], b[4];
#pragma unroll
      for (int i = 0; i < 4; ++i)
        a[i] = *(const bf16x8*)(As + (wr * 64 + i * 16 + (lane & 15)) * 64 + ko);
#pragma unroll
      for (int i = 0; i < 4; ++i)
        b[i] = *(const bf16x8*)(Bs + (wc * 64 + i * 16 + (lane & 15)) * 64 + ko);
#pragma unroll
      for (int mi = 0; mi < 4; ++mi)
#pragma unroll
        for (int ni = 0; ni < 4; ++ni)
          acc[mi][ni] = __builtin_amdgcn_mfma_f32_16x16x32_bf16(a[mi], b[ni],
                                                                acc[mi][ni], 0, 0, 0);
    }
    __syncthreads();
  }

  const int r0 = by * 128 + wr * 64 + ((lane >> 4) << 2);
  const int c0 = bx * 128 + wc * 64 + (lane & 15);
#pragma unroll
  for (int ni = 0; ni < 4; ++ni) {
    const int c = c0 + ni * 16;
    const float bv = bias[c];
    if constexpr (EPI == 0) {
      const int sel = c >> 11, cc = c & 2047, h = cc >> 7, d = cc & 127;
#pragma unroll
      for (int mi = 0; mi < 4; ++mi) {
        const int r = r0 + mi * 16;
        const int bb = r >> 11, t = r & 2047;
        if (sel == 2) {
          bf16x4 pv;
#pragma unroll
          for (int j = 0; j < 4; ++j) pv[j] = (__bf16)(acc[mi][ni][j] + bv);
          *(bf16x4*)(Vtb + ((size_t)(bb * 16 + h) * 128 + d) * 2048 + t) = pv;
        } else {
          __bf16* dst = (sel == 0 ? Qb : Kb) + ((size_t)(bb * 16 + h) * 2048 + t) * 128 + d;
          const float sc = (sel == 0) ? 0.08838834764831845f : 1.0f;  // 1/sqrt(128)
#pragma unroll
          for (int j = 0; j < 4; ++j)
            dst[(size_t)j * 128] = (__bf16)((acc[mi][ni][j] + bv) * sc);
        }
      }
    } else {
#pragma unroll
      for (int mi = 0; mi < 4; ++mi) {
        const int r = r0 + mi * 16;
#pragma unroll
        for (int j = 0; j < 4; ++j)
          Out[(size_t)(r + j) * NCOLS + c] = acc[mi][ni][j] + bv;
      }
    }
  }
}

// ---------------- causal flash attention (persistent, balanced, pipelined) ----
// grid: 768 blocks (3/CU). Work items: 2048 (bh, qt) pairs sorted heavy-first
// (qt = 31 - item/64), snake-assigned so per-block work is ~constant.
// Per item: 4 waves x 16 q-rows, KVBLK=64, XOR-swizzled LDS, async-stage split.
__global__ __launch_bounds__(256, 3)
void attn_fwd(const __bf16* __restrict__ Qb, const __bf16* __restrict__ Kb,
              const __bf16* __restrict__ Vtb, __bf16* __restrict__ Yb) {
  const int tid = threadIdx.x, lane = tid & 63, w = tid >> 6;
  const int l15 = lane & 15, g = lane >> 4;
  const int kxor = (l15 & 7) << 4;  // swizzle for rows where row&7 == l15&7
  __shared__ __align__(16) __bf16 Kl[64 * 128];    // K tile  [64][128], swz
  __shared__ __align__(16) __bf16 Vl[128 * 64];    // V^T tile[128][64], swz
  __shared__ __align__(16) __bf16 Pl[4][16 * 64];  // per-wave P [16][64], swz
  char* const Klc = (char*)Kl;
  char* const Vlc = (char*)Vl;
  char* const Plw = (char*)Pl[w];

  const int G = (int)gridDim.x;
  for (int r = 0;; ++r) {
    const int pos = (r & 1) ? (G - 1 - (int)blockIdx.x) : (int)blockIdx.x;
    const int item = r * G + pos;
    if (item >= 2048) break;
    const int qt = 31 - (item >> 6);  // heavy first
    const int bh = item & 63;
    const int bidx = bh >> 4, h = bh & 15;

    const __bf16* Qh = Qb + ((size_t)bh * 2048 + qt * 64) * 128;
    const __bf16* Kh = Kb + (size_t)bh * 2048 * 128;
    const __bf16* Vh = Vtb + (size_t)bh * 128 * 2048;

    // Q fragments: A-frag row = l15, k = kk*32 + g*8
    bf16x8 qf[4];
    {
      const int qrow = w * 16 + l15;
#pragma unroll
      for (int kk = 0; kk < 4; ++kk)
        qf[kk] = *(const bf16x8*)(Qh + (size_t)qrow * 128 + kk * 32 + g * 8);
    }

    // prologue: stage tile 0 (loads issued before the barrier to overlap)
    {
      uint4 k0[4], v0[4];
#pragma unroll
      for (int c = 0; c < 4; ++c) {
        const int idx = c * 256 + tid;
        k0[c] = *(const uint4*)(Kh + (size_t)(idx >> 4) * 128 + (idx & 15) * 8);
        v0[c] = *(const uint4*)(Vh + (size_t)(idx >> 3) * 2048 + (idx & 7) * 8);
      }
      __syncthreads();  // previous item's readers done
#pragma unroll
      for (int c = 0; c < 4; ++c) {
        const int idx = c * 256 + tid;
        { const int row = idx >> 4, colB = (idx & 15) * 16;
          *(uint4*)(Klc + row * 256 + (colB ^ ((row & 7) << 4))) = k0[c]; }
        { const int row = idx >> 3, colB = (idx & 7) * 16;
          *(uint4*)(Vlc + row * 128 + (colB ^ ((row & 7) << 4))) = v0[c]; }
      }
      __syncthreads();
    }

    f32x4 accO[8] = {};
    float mrow[4], lrow[4];
#pragma unroll
    for (int j = 0; j < 4; ++j) { mrow[j] = -3.0e38f; lrow[j] = 0.f; }

    for (int kvt = 0; kvt <= qt; ++kvt) {
      const bool pf = (kvt < qt);
      uint4 kreg[4], vreg[4];
      if (pf) {  // issue next tile's loads NOW; written to LDS after barrier
        const int kv0n = (kvt + 1) * 64;
#pragma unroll
        for (int c = 0; c < 4; ++c) {
          const int idx = c * 256 + tid;
          kreg[c] = *(const uint4*)(Kh + (size_t)(kv0n + (idx >> 4)) * 128 + (idx & 15) * 8);
          vreg[c] = *(const uint4*)(Vh + (size_t)(idx >> 3) * 2048 + kv0n + (idx & 7) * 8);
        }
      }

      // S = Q K^T : acc col = kv (l15 + n*16), row = q (g*4 + j)
      f32x4 s[4] = {};
#pragma unroll
      for (int kk = 0; kk < 4; ++kk) {
        const int colB = kk * 64 + g * 16;
#pragma unroll
        for (int n = 0; n < 4; ++n) {
          const int row = n * 16 + l15;
          bf16x8 bf = *(const bf16x8*)(Klc + row * 256 + (colB ^ kxor));
          s[n] = __builtin_amdgcn_mfma_f32_16x16x32_bf16(qf[kk], bf, s[n], 0, 0, 0);
        }
      }

      if (kvt == qt) {  // diagonal tile: causal mask
        const int qg = qt * 64 + w * 16 + (g << 2);
        const int kvg = kvt * 64 + l15;
#pragma unroll
        for (int n = 0; n < 4; ++n)
#pragma unroll
          for (int j = 0; j < 4; ++j)
            if (kvg + n * 16 > qg + j) s[n][j] = -3.0e38f;
      }

      // wave-parallel row max/sum over 64 cols
      float pm[4];
#pragma unroll
      for (int j = 0; j < 4; ++j)
        pm[j] = fmaxf(fmaxf(s[0][j], s[1][j]), fmaxf(s[2][j], s[3][j]));
#pragma unroll
      for (int off = 1; off < 16; off <<= 1)
#pragma unroll
        for (int j = 0; j < 4; ++j)
          pm[j] = fmaxf(pm[j], __shfl_xor(pm[j], off, 64));

      float corr[4];
#pragma unroll
      for (int j = 0; j < 4; ++j) {
        const float mnew = fmaxf(mrow[j], pm[j]);
        corr[j] = exp2f((mrow[j] - mnew) * LOG2E);
        mrow[j] = mnew;
      }

      float rs[4] = {0.f, 0.f, 0.f, 0.f};
#pragma unroll
      for (int n = 0; n < 4; ++n)
#pragma unroll
        for (int j = 0; j < 4; ++j) {
          const float p = exp2f((s[n][j] - mrow[j]) * LOG2E);
          s[n][j] = p;
          rs[j] += p;
        }
#pragma unroll
      for (int off = 1; off < 16; off <<= 1)
#pragma unroll
        for (int j = 0; j < 4; ++j) rs[j] += __shfl_xor(rs[j], off, 64);
#pragma unroll
      for (int j = 0; j < 4; ++j) lrow[j] = lrow[j] * corr[j] + rs[j];

#pragma unroll
      for (int n = 0; n < 8; ++n)
#pragma unroll
        for (int j = 0; j < 4; ++j) accO[n][j] *= corr[j];

      // repack P (wave-local LDS, swizzled; no barrier needed)
#pragma unroll
      for (int n = 0; n < 4; ++n)
#pragma unroll
        for (int j = 0; j < 4; ++j) {
          const int row = g * 4 + j;
          const int colB = (n * 16 + l15) * 2;
          *(__bf16*)(Plw + row * 128 + (colB ^ ((row & 7) << 4))) = (__bf16)s[n][j];
        }

      // O += P @ V
#pragma unroll
      for (int kk = 0; kk < 2; ++kk) {
        const int colB = kk * 64 + g * 16;
        bf16x8 af = *(const bf16x8*)(Plw + l15 * 128 + (colB ^ kxor));
#pragma unroll
        for (int n = 0; n < 8; ++n) {
          const int row = n * 16 + l15;
          bf16x8 bf = *(const bf16x8*)(Vlc + row * 128 + (colB ^ kxor));
          accO[n] = __builtin_amdgcn_mfma_f32_16x16x32_bf16(af, bf, accO[n], 0, 0, 0);
        }
      }

      if (pf) {  // publish prefetched tile
        __syncthreads();
#pragma unroll
        for (int c = 0; c < 4; ++c) {
          const int idx = c * 256 + tid;
          { const int row = idx >> 4, colB = (idx & 15) * 16;
            *(uint4*)(Klc + row * 256 + (colB ^ ((row & 7) << 4))) = kreg[c]; }
          { const int row = idx >> 3, colB = (idx & 7) * 16;
            *(uint4*)(Vlc + row * 128 + (colB ^ ((row & 7) << 4))) = vreg[c]; }
        }
        __syncthreads();
      }
    }

    // normalize and write y[b, t, h*128 + d] bf16
    float rl[4];
#pragma unroll
    for (int j = 0; j < 4; ++j) rl[j] = 1.0f / lrow[j];
    const int t0 = qt * 64 + w * 16 + (g << 2);
#pragma unroll
    for (int n = 0; n < 8; ++n)
#pragma unroll
      for (int j = 0; j < 4; ++j)
        Yb[((size_t)bidx * 2048 + t0 + j) * 2048 + h * 128 + n * 16 + l15] =
            (__bf16)(accO[n][j] * rl[j]);
  }
}

// ---------------- launch ----------------
extern "C" void kernel_launch(void* const* d_in, const int* in_sizes, int n_in,
                              void* d_out, int out_size, void* d_ws, size_t ws_size,
                              hipStream_t stream) {
  const float* x      = (const float*)d_in[0];
  const float* w_attn = (const float*)d_in[1];
  const float* b_attn = (const float*)d_in[2];
  const float* w_proj = (const float*)d_in[3];
  const float* b_proj = (const float*)d_in[4];
  float* out = (float*)d_out;

  __bf16* Qb  = (__bf16*)d_ws;                 // [B,H,T,D]
  __bf16* Kb  = Qb  + (size_t)16777216;        // [B,H,T,D]
  __bf16* Vtb = Kb  + (size_t)16777216;        // [B,H,D,T]
  __bf16* XYb = Vtb + (size_t)16777216;        // x_bf16, later y_bf16 [B,T,C]
  __bf16* Wt  = XYb + (size_t)16777216;        // w_attn^T / w_proj^T

  cvt4<<<dim3(16384), dim3(256), 0, stream>>>(x, XYb, 4194304);
  transcvt<<<dim3(192, 64), dim3(32, 8), 0, stream>>>(w_attn, Wt, 2048, 6144);
  gemm_bt<0, 6144><<<dim3(48, 64), dim3(256), 0, stream>>>(XYb, Wt, b_attn,
                                                           Qb, Kb, Vtb, nullptr);
  transcvt<<<dim3(64, 64), dim3(32, 8), 0, stream>>>(w_proj, Wt, 2048, 2048);
  attn_fwd<<<dim3(768), dim3(256), 0, stream>>>(Qb, Kb, Vtb, XYb);
  gemm_bt<1, 2048><<<dim3(16, 64), dim3(256), 0, stream>>>(XYb, Wt, b_proj,
                                                           nullptr, nullptr, nullptr, out);
}

// Round 3
// 532.330 us; speedup vs baseline: 1.4721x; 1.4390x over previous
//
#include <hip/hip_runtime.h>

typedef __bf16 bf16x8 __attribute__((ext_vector_type(8)));
typedef __bf16 bf16x4 __attribute__((ext_vector_type(4)));
typedef float  f32x4  __attribute__((ext_vector_type(4)));
typedef float  f32x16 __attribute__((ext_vector_type(16)));
typedef unsigned u32x4 __attribute__((ext_vector_type(4)));

#define LOG2E 1.4426950408889634f

__device__ __forceinline__ void gload16(const void* g, void* l) {
  __builtin_amdgcn_global_load_lds((const __attribute__((address_space(1))) void*)g,
                                   (__attribute__((address_space(3))) void*)l, 16, 0, 0);
}

__device__ __forceinline__ unsigned pk(float lo, float hi) {
  unsigned short lu = __builtin_bit_cast(unsigned short, (__bf16)lo);
  unsigned short hu = __builtin_bit_cast(unsigned short, (__bf16)hi);
  return (unsigned)lu | ((unsigned)hu << 16);
}

// ---------------- f32 -> bf16 elementwise convert (x) ----------------
__global__ __launch_bounds__(256) void cvt4(const float* __restrict__ in,
                                            __bf16* __restrict__ outp, int n4) {
  int i = blockIdx.x * blockDim.x + threadIdx.x;
  if (i < n4) {
    float4 v = ((const float4*)in)[i];
    bf16x4 o = { (__bf16)v.x, (__bf16)v.y, (__bf16)v.z, (__bf16)v.w };
    *(bf16x4*)(outp + (size_t)i * 4) = o;
  }
}

// ---------------- f32 [K,N] -> bf16 [N,K] transpose-convert ----------------
__global__ __launch_bounds__(256) void transcvt(const float* __restrict__ w,
                                                __bf16* __restrict__ wt,
                                                int K, int N) {
  __shared__ float tile[32][33];
  const int n0 = blockIdx.x * 32, k0 = blockIdx.y * 32;
  const int tx = threadIdx.x, ty = threadIdx.y;
#pragma unroll
  for (int i = 0; i < 4; ++i)
    tile[ty + i * 8][tx] = w[(size_t)(k0 + ty + i * 8) * N + n0 + tx];
  __syncthreads();
#pragma unroll
  for (int i = 0; i < 4; ++i)
    wt[(size_t)(n0 + ty + i * 8) * K + k0 + tx] = (__bf16)tile[tx][ty + i * 8];
}

// ---------------- bf16 GEMM: C = A[M,K] * Bt[N,K]^T (+bias) ----------------
template <int EPI, int NCOLS>
__global__ __launch_bounds__(256, 2)
void gemm_bt(const __bf16* __restrict__ A, const __bf16* __restrict__ Bt,
             const float* __restrict__ bias,
             __bf16* __restrict__ Qb, __bf16* __restrict__ Kb,
             __bf16* __restrict__ Vtb, float* __restrict__ Out) {
  constexpr int K = 2048;
  __shared__ __align__(16) __bf16 As[128 * 64];
  __shared__ __align__(16) __bf16 Bs[128 * 64];
  const int tid = threadIdx.x, lane = tid & 63, w = tid >> 6;
  const int wr = w >> 1, wc = w & 1;
  const int by = blockIdx.y, bx = blockIdx.x;
  const __bf16* Ab = A + (size_t)by * 128 * K;
  const __bf16* Bb = Bt + (size_t)bx * 128 * K;
  f32x4 acc[4][4] = {};

  for (int k0 = 0; k0 < K; k0 += 64) {
#pragma unroll
    for (int c = 0; c < 4; ++c) {
      int idx = c * 256 + tid;
      int row = idx >> 3, col = (idx & 7) * 8;
      gload16(Ab + (size_t)row * K + k0 + col, (void*)(As + idx * 8));
      gload16(Bb + (size_t)row * K + k0 + col, (void*)(Bs + idx * 8));
    }
    __syncthreads();
#pragma unroll
    for (int kk = 0; kk < 64; kk += 32) {
      const int ko = kk + (lane >> 4) * 8;
      bf16x8 a[4], b[4];
#pragma unroll
      for (int i = 0; i < 4; ++i)
        a[i] = *(const bf16x8*)(As + (wr * 64 + i * 16 + (lane & 15)) * 64 + ko);
#pragma unroll
      for (int i = 0; i < 4; ++i)
        b[i] = *(const bf16x8*)(Bs + (wc * 64 + i * 16 + (lane & 15)) * 64 + ko);
#pragma unroll
      for (int mi = 0; mi < 4; ++mi)
#pragma unroll
        for (int ni = 0; ni < 4; ++ni)
          acc[mi][ni] = __builtin_amdgcn_mfma_f32_16x16x32_bf16(a[mi], b[ni],
                                                                acc[mi][ni], 0, 0, 0);
    }
    __syncthreads();
  }

  const int r0 = by * 128 + wr * 64 + ((lane >> 4) << 2);
  const int c0 = bx * 128 + wc * 64 + (lane & 15);
#pragma unroll
  for (int ni = 0; ni < 4; ++ni) {
    const int c = c0 + ni * 16;
    const float bv = bias[c];
    if constexpr (EPI == 0) {
      const int sel = c >> 11, cc = c & 2047, h = cc >> 7, d = cc & 127;
#pragma unroll
      for (int mi = 0; mi < 4; ++mi) {
        const int r = r0 + mi * 16;
        const int bb = r >> 11, t = r & 2047;
        if (sel == 2) {
          bf16x4 pv;
#pragma unroll
          for (int j = 0; j < 4; ++j) pv[j] = (__bf16)(acc[mi][ni][j] + bv);
          *(bf16x4*)(Vtb + ((size_t)(bb * 16 + h) * 128 + d) * 2048 + t) = pv;
        } else {
          __bf16* dst = (sel == 0 ? Qb : Kb) + ((size_t)(bb * 16 + h) * 2048 + t) * 128 + d;
          const float sc = (sel == 0) ? 0.08838834764831845f : 1.0f;  // 1/sqrt(128)
#pragma unroll
          for (int j = 0; j < 4; ++j)
            dst[(size_t)j * 128] = (__bf16)((acc[mi][ni][j] + bv) * sc);
        }
      }
    } else {
#pragma unroll
      for (int mi = 0; mi < 4; ++mi) {
        const int r = r0 + mi * 16;
#pragma unroll
        for (int j = 0; j < 4; ++j)
          Out[(size_t)(r + j) * NCOLS + c] = acc[mi][ni][j] + bv;
      }
    }
  }
}

// ---------------- causal flash attention: m214-style 8-warp 32x32 ----------
// Swapped QK^T (S^T[kv,q], q = lane&31) -> softmax row is lane-local + one
// shfl_xor(32). P repacked to PV B-frags in-register. O^T orientation so
// corr/l are lane-local. Double-buffered K/V LDS, 1 barrier/tile.
// Persistent grid: 512 items = (bh, qb), snake heavy-first -> 36 tiles/block.
__global__ __launch_bounds__(512, 2)
void attn_fwd(const __bf16* __restrict__ Qb, const __bf16* __restrict__ Kb,
              const __bf16* __restrict__ Vtb, __bf16* __restrict__ Yb) {
  __shared__ __align__(16) char lds[65536];  // 2 x (K 16KB + V^T 16KB)
  const int tid = threadIdx.x;
  const int lane = tid & 63, w = tid >> 6;   // 8 warps
  const int l31 = lane & 31, hi = lane >> 5;
  const int kx = (l31 & 7) << 4;             // read-side XOR swizzle

  const int G = (int)gridDim.x;
  for (int rr = 0;; ++rr) {
    const int pos = (rr & 1) ? (G - 1 - (int)blockIdx.x) : (int)blockIdx.x;
    const int item = rr * G + pos;
    if (item >= 512) break;
    const int qb = 7 - (item >> 6);          // heavy first
    const int bh = item & 63;
    const int bidx = bh >> 4, h = bh & 15;
    const int nt = (qb + 1) * 4;

    const __bf16* Qh = Qb + ((size_t)bh * 2048 + qb * 256) * 128;
    const __bf16* Kh = Kb + (size_t)bh * 2048 * 128;
    const __bf16* Vh = Vtb + (size_t)bh * 128 * 2048;

    // Q fragments: B-operand rows, lane holds Q[q=l31, d = ds*16 + hi*8 + e]
    bf16x8 qf[8];
    {
      const __bf16* qrow = Qh + (size_t)(w * 32 + l31) * 128 + hi * 8;
#pragma unroll
      for (int ds = 0; ds < 8; ++ds) qf[ds] = *(const bf16x8*)(qrow + ds * 16);
    }

    // prologue: stage tile 0 -> buf 0
    {
      uint4 kr[2], vr[2];
#pragma unroll
      for (int c = 0; c < 2; ++c) {
        const int idx = c * 512 + tid;
        kr[c] = *(const uint4*)(Kh + (size_t)(idx >> 4) * 128 + (idx & 15) * 8);
        vr[c] = *(const uint4*)(Vh + (size_t)(idx >> 3) * 2048 + (idx & 7) * 8);
      }
      __syncthreads();  // previous item's readers done
      char* K0 = lds;
      char* V0 = lds + 16384;
#pragma unroll
      for (int c = 0; c < 2; ++c) {
        const int idx = c * 512 + tid;
        { const int row = idx >> 4, colB = (idx & 15) * 16;
          *(uint4*)(K0 + row * 256 + (colB ^ ((row & 7) << 4))) = kr[c]; }
        { const int row = idx >> 3, colB = (idx & 7) * 16;
          *(uint4*)(V0 + row * 128 + (colB ^ ((row & 7) << 4))) = vr[c]; }
      }
      __syncthreads();
    }

    f32x16 accO[4] = {};        // O^T[d = db*32 + reg-row, q = l31]
    float mL = -3.0e38f, lsum = 0.f;
    const int qg  = qb * 256 + w * 32 + l31;  // this lane's q (S^T column)
    const int qwb = qb * 256 + w * 32;        // warp's min q

    for (int t = 0; t < nt; ++t) {
      const int kv0 = t * 64;
      char* Kc = lds + (t & 1) * 32768;
      char* Vc = Kc + 16384;
      const bool pf = (t + 1 < nt);
      uint4 kr[2], vr[2];
      if (pf) {  // T14: issue next tile's loads now, write to LDS after compute
        const int kvn = kv0 + 64;
#pragma unroll
        for (int c = 0; c < 2; ++c) {
          const int idx = c * 512 + tid;
          kr[c] = *(const uint4*)(Kh + (size_t)(kvn + (idx >> 4)) * 128 + (idx & 15) * 8);
          vr[c] = *(const uint4*)(Vh + (size_t)(idx >> 3) * 2048 + kvn + (idx & 7) * 8);
        }
      }

      // S^T = K Q^T : col = q = l31, row(reg r) = (r&3)+8*(r>>2)+4*hi (+32*frag)
      f32x16 s0 = {}, s1 = {};
      __builtin_amdgcn_s_setprio(1);
#pragma unroll
      for (int ds = 0; ds < 8; ++ds) {
        const int cb = (ds * 32 + hi * 16) ^ kx;
        bf16x8 k0 = *(const bf16x8*)(Kc + l31 * 256 + cb);
        bf16x8 k1 = *(const bf16x8*)(Kc + (32 + l31) * 256 + cb);
        s0 = __builtin_amdgcn_mfma_f32_32x32x16_bf16(k0, qf[ds], s0, 0, 0, 0);
        s1 = __builtin_amdgcn_mfma_f32_32x32x16_bf16(k1, qf[ds], s1, 0, 0, 0);
      }
      __builtin_amdgcn_s_setprio(0);

      // log2 domain + causal mask (diagonal tiles only)
      f32x16 a0, a1;
#pragma unroll
      for (int r = 0; r < 16; ++r) { a0[r] = s0[r] * LOG2E; a1[r] = s1[r] * LOG2E; }
      if (kv0 + 63 > qwb) {
#pragma unroll
        for (int r = 0; r < 16; ++r) {
          const int kvr = kv0 + (r & 3) + 8 * (r >> 2) + 4 * hi;
          if (kvr > qg)      a0[r] = -1.0e38f;
          if (kvr + 32 > qg) a1[r] = -1.0e38f;
        }
      }

      // row max: 31 local + 1 shfl (partner holds other 32 kv of this q-row)
      float pm = a0[0];
#pragma unroll
      for (int r = 1; r < 16; ++r) pm = fmaxf(pm, a0[r]);
#pragma unroll
      for (int r = 0; r < 16; ++r) pm = fmaxf(pm, a1[r]);
      pm = fmaxf(pm, __shfl_xor(pm, 32, 64));

      // T13 defer-max: skip O rescale unless max grew past threshold (8 nats)
      if (!__all(pm - mL <= 11.5f)) {
        const float mn = fmaxf(mL, pm);
        const float corr = exp2f(mL - mn);
        mL = mn;
        lsum *= corr;
#pragma unroll
        for (int db = 0; db < 4; ++db)
#pragma unroll
          for (int r = 0; r < 16; ++r) accO[db][r] *= corr;
      }

      float p[32];
      float rs = 0.f;
#pragma unroll
      for (int r = 0; r < 16; ++r) { p[r] = exp2f(a0[r] - mL); rs += p[r]; }
#pragma unroll
      for (int r = 0; r < 16; ++r) { p[16 + r] = exp2f(a1[r] - mL); rs += p[16 + r]; }
      rs += __shfl_xor(rs, 32, 64);
      lsum += rs;

      // pack P -> PV B-frags: pa[ks] elem e = P[q=l31, kv = ks*16 + hi*8 + e]
      bf16x8 pa[4];
#pragma unroll
      for (int f = 0; f < 2; ++f) {
        unsigned wv[8];
#pragma unroll
        for (int i = 0; i < 8; ++i)
          wv[i] = pk(p[f * 16 + 2 * i], p[f * 16 + 2 * i + 1]);
        // exchange complementary quads with partner lane (l ^ 32)
        const unsigned x0 = (unsigned)__shfl_xor((int)(hi ? wv[0] : wv[2]), 32, 64);
        const unsigned x1 = (unsigned)__shfl_xor((int)(hi ? wv[1] : wv[3]), 32, 64);
        const unsigned x2 = (unsigned)__shfl_xor((int)(hi ? wv[4] : wv[6]), 32, 64);
        const unsigned x3 = (unsigned)__shfl_xor((int)(hi ? wv[5] : wv[7]), 32, 64);
        u32x4 A, B;
        A[0] = hi ? x0 : wv[0];  A[1] = hi ? x1 : wv[1];
        A[2] = hi ? wv[2] : x0;  A[3] = hi ? wv[3] : x1;
        B[0] = hi ? x2 : wv[4];  B[1] = hi ? x3 : wv[5];
        B[2] = hi ? wv[6] : x2;  B[3] = hi ? wv[7] : x3;
        pa[f * 2 + 0] = __builtin_bit_cast(bf16x8, A);
        pa[f * 2 + 1] = __builtin_bit_cast(bf16x8, B);
      }

      // O^T += V^T P^T : A = V^T rows (d), B = pa, acc col = q (lane-local)
      __builtin_amdgcn_s_setprio(1);
#pragma unroll
      for (int ks = 0; ks < 4; ++ks) {
        const int cb = (ks * 32 + hi * 16) ^ kx;
#pragma unroll
        for (int db = 0; db < 4; ++db) {
          bf16x8 vf = *(const bf16x8*)(Vc + (db * 32 + l31) * 128 + cb);
          accO[db] = __builtin_amdgcn_mfma_f32_32x32x16_bf16(vf, pa[ks], accO[db], 0, 0, 0);
        }
      }
      __builtin_amdgcn_s_setprio(0);

      if (pf) {  // publish prefetched tile into the other buffer
        char* Kn = lds + ((t + 1) & 1) * 32768;
        char* Vn = Kn + 16384;
#pragma unroll
        for (int c = 0; c < 2; ++c) {
          const int idx = c * 512 + tid;
          { const int row = idx >> 4, colB = (idx & 15) * 16;
            *(uint4*)(Kn + row * 256 + (colB ^ ((row & 7) << 4))) = kr[c]; }
          { const int row = idx >> 3, colB = (idx & 7) * 16;
            *(uint4*)(Vn + row * 128 + (colB ^ ((row & 7) << 4))) = vr[c]; }
        }
      }
      __syncthreads();
    }

    // epilogue: Y[b, q, h*128 + d] = O^T[d, q] / l   (d = db*32 + 8j + 4hi + i)
    const float rl = 1.0f / lsum;
    __bf16* Yw = Yb + ((size_t)bidx * 2048 + qg) * 2048 + h * 128;
#pragma unroll
    for (int db = 0; db < 4; ++db)
#pragma unroll
      for (int j = 0; j < 4; ++j) {
        bf16x4 o;
#pragma unroll
        for (int i = 0; i < 4; ++i) o[i] = (__bf16)(accO[db][4 * j + i] * rl);
        *(bf16x4*)(Yw + db * 32 + 8 * j + 4 * hi) = o;
      }
  }
}

// ---------------- launch ----------------
extern "C" void kernel_launch(void* const* d_in, const int* in_sizes, int n_in,
                              void* d_out, int out_size, void* d_ws, size_t ws_size,
                              hipStream_t stream) {
  const float* x      = (const float*)d_in[0];
  const float* w_attn = (const float*)d_in[1];
  const float* b_attn = (const float*)d_in[2];
  const float* w_proj = (const float*)d_in[3];
  const float* b_proj = (const float*)d_in[4];
  float* out = (float*)d_out;

  __bf16* Qb  = (__bf16*)d_ws;                 // [B,H,T,D] (pre-scaled 1/sqrt(D))
  __bf16* Kb  = Qb  + (size_t)16777216;        // [B,H,T,D]
  __bf16* Vtb = Kb  + (size_t)16777216;        // [B,H,D,T]
  __bf16* XYb = Vtb + (size_t)16777216;        // x_bf16, later y_bf16 [B,T,C]
  __bf16* Wt  = XYb + (size_t)16777216;        // w_attn^T / w_proj^T

  cvt4<<<dim3(16384), dim3(256), 0, stream>>>(x, XYb, 4194304);
  transcvt<<<dim3(192, 64), dim3(32, 8), 0, stream>>>(w_attn, Wt, 2048, 6144);
  gemm_bt<0, 6144><<<dim3(48, 64), dim3(256), 0, stream>>>(XYb, Wt, b_attn,
                                                           Qb, Kb, Vtb, nullptr);
  transcvt<<<dim3(64, 64), dim3(32, 8), 0, stream>>>(w_proj, Wt, 2048, 2048);
  attn_fwd<<<dim3(256), dim3(512), 0, stream>>>(Qb, Kb, Vtb, XYb);
  gemm_bt<1, 2048><<<dim3(16, 64), dim3(256), 0, stream>>>(XYb, Wt, b_proj,
                                                           nullptr, nullptr, nullptr, out);
}